// Round 3
// baseline (130.210 us; speedup 1.0000x reference)
//
#include <hip/hip_runtime.h>
#include <hip/hip_bf16.h>

#define NB 16
#define NC 128
#define NN 2048
#define NF 64
#define NEG_SLOPE 0.33f
#define MASK_VAL (-9.0e15f)

typedef float    f32x4 __attribute__((ext_vector_type(4)));
typedef _Float16 f16x4 __attribute__((ext_vector_type(4)));
typedef _Float16 f16x8 __attribute__((ext_vector_type(8)));

__device__ __forceinline__ float lrelu(float x) {
    return x > 0.0f ? x : x * NEG_SLOPE;
}

// Kernel 1: Wh = h^T @ W in fp32 (VALU, LDS-tiled); emit WhT f16 [b][f][n],
// s1 = Wh@a1, s2 = Wh@a2 in fp32.  (unchanged)
__global__ __launch_bounds__(256) void k_precompute(
    const float* __restrict__ h, const float* __restrict__ W,
    const float* __restrict__ a, _Float16* __restrict__ wht,
    float* __restrict__ s1g, float* __restrict__ s2g)
{
    __shared__ float Wl[64 * 64];
    __shared__ float ht[64 * 129];

    const int t = threadIdx.x;
    const int b = blockIdx.x >> 5;
    const int n0 = (blockIdx.x & 31) << 6;
    const int lane = t & 63, cg = t >> 6;

    #pragma unroll 8
    for (int k = 0; k < 32; ++k) {
        const int c = cg * 32 + k;
        ht[lane * 129 + c] = h[(size_t)(b * NC + c) * NN + n0 + lane];
    }

    const int fg = t & 15, ns = t >> 4;
    f32x4 acc[4] = {};
    for (int half = 0; half < 2; ++half) {
        if (half) __syncthreads();
        #pragma unroll
        for (int k = 0; k < 4; ++k) {
            const int idx = k * 1024 + t * 4;
            *(f32x4*)&Wl[idx] = *(const f32x4*)&W[half * 4096 + idx];
        }
        __syncthreads();
        #pragma unroll 4
        for (int c2 = 0; c2 < 64; ++c2) {
            const f32x4 wv = *(const f32x4*)&Wl[c2 * 64 + fg * 4];
            #pragma unroll
            for (int m = 0; m < 4; ++m) {
                const float hv = ht[(ns * 4 + m) * 129 + half * 64 + c2];
                acc[m] += wv * hv;
            }
        }
    }

    const f32x4 a1v = *(const f32x4*)&a[fg * 4];
    const f32x4 a2v = *(const f32x4*)&a[NF + fg * 4];
    #pragma unroll
    for (int m = 0; m < 4; ++m) {
        float p1 = acc[m].x * a1v.x + acc[m].y * a1v.y + acc[m].z * a1v.z + acc[m].w * a1v.w;
        float p2 = acc[m].x * a2v.x + acc[m].y * a2v.y + acc[m].z * a2v.z + acc[m].w * a2v.w;
        #pragma unroll
        for (int d = 1; d < 16; d <<= 1) {
            p1 += __shfl_xor(p1, d, 64);
            p2 += __shfl_xor(p2, d, 64);
        }
        if (fg == 0) {
            const int n = n0 + ns * 4 + m;
            s1g[(size_t)b * NN + n] = p1;
            s2g[(size_t)b * NN + n] = p2;
        }
    }
    #pragma unroll
    for (int q = 0; q < 4; ++q) {
        f16x4 v;
        v[0] = (_Float16)acc[0][q]; v[1] = (_Float16)acc[1][q];
        v[2] = (_Float16)acc[2][q]; v[3] = (_Float16)acc[3][q];
        const int f = fg * 4 + q;
        *(f16x4*)&wht[((size_t)b * NF + f) * NN + n0 + ns * 4] = v;
    }
}

// Kernel 2: shift-invariant softmax with precomputed upper-bound shift
// M_i = lrelu(s1_i + max_j s2_j)  (>= every e_ij since lrelu is monotone).
// No online max, no alpha rescale, no per-chunk cross-lane ops.
// g streamed exactly once with depth-2 register prefetch; P chunk double-
// buffered in LDS; one barrier per chunk; 16x16x32 f16 MFMA for P@WhT.
__global__ __launch_bounds__(512, 8) void k_attn(
    const float* __restrict__ g, const _Float16* __restrict__ wht,
    const float* __restrict__ s1g, const float* __restrict__ s2g,
    float* __restrict__ out)
{
    __shared__ float s2b[NN];                   // 8 KB
    __shared__ float s1b[16];
    __shared__ float Srow[16];
    __shared__ float wred[8];
    __shared__ _Float16 Pc[2 * 16 * 264];       // dbuf P chunk, padded stride (16.5 KB)
    __shared__ float scratch[1024];             // cross-wave acc reduce (4 KB)

    const int t = threadIdx.x;
    const int lane = t & 63;
    const int w = t >> 6;                       // wave 0..7
    const int b = blockIdx.x >> 7;
    const int i0 = (blockIdx.x & 127) << 4;

    // prologue: s2 -> LDS, and one-time per-batch max(s2) reduction
    const f32x4 s2v = *(const f32x4*)&s2g[(size_t)b * NN + t * 4];
    *(f32x4*)&s2b[t * 4] = s2v;
    if (t < 16) s1b[t] = s1g[(size_t)b * NN + i0 + t];
    float lm = fmaxf(fmaxf(s2v.x, s2v.y), fmaxf(s2v.z, s2v.w));
    #pragma unroll
    for (int d = 1; d < 64; d <<= 1) lm = fmaxf(lm, __shfl_xor(lm, d, 64));
    if (lane == 0) wred[w] = lm;
    __syncthreads();
    float S2MAX = wred[0];
    #pragma unroll
    for (int q = 1; q < 8; ++q) S2MAX = fmaxf(S2MAX, wred[q]);

    const float* gb = g + (size_t)b * NN * NN;
    const float* gr0 = gb + (size_t)(i0 + w) * NN + lane * 4;
    const float* gr1 = gr0 + 8 * NN;
    const float s1r0 = s1b[w];
    const float s1r1 = s1b[w + 8];
    const float Mr0 = lrelu(s1r0 + S2MAX);      // upper bound on row-w scores
    const float Mr1 = lrelu(s1r1 + S2MAX);

    const int nt = w & 3, kh = w >> 2;          // MFMA roles: n-tile, k-half
    const int arow = lane & 15;
    const int koff = (lane >> 4) * 8;
    const _Float16* wb = wht + ((size_t)b * NF + nt * 16 + arow) * NN;

    float su0 = 0.0f, su1 = 0.0f;               // per-lane partial row sums
    f32x4 acc = {0.0f, 0.0f, 0.0f, 0.0f};

    // depth-2 register prefetch ring (statically indexed after full unroll)
    f32x4 r0[2], r1[2];
    r0[0] = *(const f32x4*)gr0;
    r1[0] = *(const f32x4*)gr1;
    r0[1] = *(const f32x4*)(gr0 + 256);
    r1[1] = *(const f32x4*)(gr1 + 256);

    #pragma unroll
    for (int ch = 0; ch < 8; ++ch) {
        const int sl = ch & 1;
        const f32x4 c0 = r0[sl], c1 = r1[sl];
        if (ch < 6) {                           // refill slot with chunk ch+2
            r0[sl] = *(const f32x4*)(gr0 + (ch + 2) * 256);
            r1[sl] = *(const f32x4*)(gr1 + (ch + 2) * 256);
        }
        const int pb = sl * 16 * 264;
        const f32x4 sv = *(const f32x4*)&s2b[ch * 256 + lane * 4];

        // ---- row w ----
        {
            const float p0 = c0.x > 0.0f ? __expf(lrelu(s1r0 + sv.x) - Mr0) : 0.0f;
            const float p1 = c0.y > 0.0f ? __expf(lrelu(s1r0 + sv.y) - Mr0) : 0.0f;
            const float p2 = c0.z > 0.0f ? __expf(lrelu(s1r0 + sv.z) - Mr0) : 0.0f;
            const float p3 = c0.w > 0.0f ? __expf(lrelu(s1r0 + sv.w) - Mr0) : 0.0f;
            su0 += (p0 + p1) + (p2 + p3);
            f16x4 pv; pv[0] = (_Float16)p0; pv[1] = (_Float16)p1;
            pv[2] = (_Float16)p2; pv[3] = (_Float16)p3;
            *(f16x4*)&Pc[pb + w * 264 + lane * 4] = pv;
        }
        // ---- row w+8 ----
        {
            const float p0 = c1.x > 0.0f ? __expf(lrelu(s1r1 + sv.x) - Mr1) : 0.0f;
            const float p1 = c1.y > 0.0f ? __expf(lrelu(s1r1 + sv.y) - Mr1) : 0.0f;
            const float p2 = c1.z > 0.0f ? __expf(lrelu(s1r1 + sv.z) - Mr1) : 0.0f;
            const float p3 = c1.w > 0.0f ? __expf(lrelu(s1r1 + sv.w) - Mr1) : 0.0f;
            su1 += (p0 + p1) + (p2 + p3);
            f16x4 pv; pv[0] = (_Float16)p0; pv[1] = (_Float16)p1;
            pv[2] = (_Float16)p2; pv[3] = (_Float16)p3;
            *(f16x4*)&Pc[pb + (w + 8) * 264 + lane * 4] = pv;
        }

        __syncthreads();   // Pc[pb] ready; barrier also fences next iter's overwrite of Pc[pb^1]

        // ---- MFMA: acc += P_chunk @ WhT_chunk ----
        {
            const _Float16* wbc = wb + ch * 256;
            #pragma unroll
            for (int ks = 0; ks < 4; ++ks) {
                const int kc = kh * 128 + ks * 32;
                f16x8 af = *(const f16x8*)&Pc[pb + arow * 264 + kc + koff];
                f16x8 bf = *(const f16x8*)&wbc[kc + koff];
                acc = __builtin_amdgcn_mfma_f32_16x16x32_f16(af, bf, acc, 0, 0, 0);
            }
        }
    }

    // ---- row sums, cross-wave acc reduce, epilogue ----
    {
        float s = su0;
        #pragma unroll
        for (int d = 1; d < 64; d <<= 1) s += __shfl_xor(s, d, 64);
        if (lane == 0) Srow[w] = s;
        s = su1;
        #pragma unroll
        for (int d = 1; d < 64; d <<= 1) s += __shfl_xor(s, d, 64);
        if (lane == 0) Srow[w + 8] = s;
    }
    if (kh == 1) *(f32x4*)&scratch[(nt * 64 + lane) * 4] = acc;
    __syncthreads();
    if (kh == 0) {
        f32x4 o = *(const f32x4*)&scratch[(nt * 64 + lane) * 4];
        acc.x += o.x; acc.y += o.y; acc.z += o.z; acc.w += o.w;
        const int rbase = (lane >> 4) * 4;      // D row = (lane>>4)*4 + reg (m89-verified)
        f32x4 res;
        #pragma unroll
        for (int r2 = 0; r2 < 4; ++r2) res[r2] = acc[r2] * (1.0f / Srow[rbase + r2]);
        const int f = nt * 16 + arow;           // D col = lane&15
        *(f32x4*)&out[((size_t)b * NF + f) * NN + (size_t)(i0 + rbase)] = res;
    }
}

extern "C" void kernel_launch(void* const* d_in, const int* in_sizes, int n_in,
                              void* d_out, int out_size, void* d_ws, size_t ws_size,
                              hipStream_t stream)
{
    (void)in_sizes; (void)n_in; (void)out_size; (void)ws_size;
    const float* h = (const float*)d_in[0];
    const float* g = (const float*)d_in[1];
    const float* W = (const float*)d_in[2];
    const float* a = (const float*)d_in[3];
    float* out = (float*)d_out;

    // workspace: WhT f16 (4 MiB) | s1 (128 KiB) | s2 (128 KiB)
    char* ws = (char*)d_ws;
    _Float16* wht = (_Float16*)ws;
    float* s1 = (float*)(ws + (size_t)NB * NF * NN * sizeof(_Float16));
    float* s2 = s1 + (size_t)NB * NN;

    k_precompute<<<NB * (NN / 64), 256, 0, stream>>>(h, W, a, wht, s1, s2);
    k_attn<<<NB * (NN / 16), 512, 0, stream>>>(g, wht, s1, s2, out);
}

// Round 4
// 112.652 us; speedup vs baseline: 1.1559x; 1.1559x over previous
//
#include <hip/hip_runtime.h>
#include <hip/hip_bf16.h>

#define NB 16
#define NC 128
#define NN 2048
#define NF 64
#define NEG_SLOPE 0.33f

typedef float    f32x4 __attribute__((ext_vector_type(4)));
typedef _Float16 f16x4 __attribute__((ext_vector_type(4)));
typedef _Float16 f16x8 __attribute__((ext_vector_type(8)));

__device__ __forceinline__ float lrelu(float x) {
    return fmaxf(x, x * NEG_SLOPE);   // valid leaky-relu for slope<1
}

// Kernel 1: Wh = h^T @ W in fp32 (VALU, LDS-tiled); emit WhT f16 [b][f][n],
// s1 = Wh@a1, s2 = Wh@a2 in fp32.  (unchanged)
__global__ __launch_bounds__(256) void k_precompute(
    const float* __restrict__ h, const float* __restrict__ W,
    const float* __restrict__ a, _Float16* __restrict__ wht,
    float* __restrict__ s1g, float* __restrict__ s2g)
{
    __shared__ float Wl[64 * 64];
    __shared__ float ht[64 * 129];

    const int t = threadIdx.x;
    const int b = blockIdx.x >> 5;
    const int n0 = (blockIdx.x & 31) << 6;
    const int lane = t & 63, cg = t >> 6;

    #pragma unroll 8
    for (int k = 0; k < 32; ++k) {
        const int c = cg * 32 + k;
        ht[lane * 129 + c] = h[(size_t)(b * NC + c) * NN + n0 + lane];
    }

    const int fg = t & 15, ns = t >> 4;
    f32x4 acc[4] = {};
    for (int half = 0; half < 2; ++half) {
        if (half) __syncthreads();
        #pragma unroll
        for (int k = 0; k < 4; ++k) {
            const int idx = k * 1024 + t * 4;
            *(f32x4*)&Wl[idx] = *(const f32x4*)&W[half * 4096 + idx];
        }
        __syncthreads();
        #pragma unroll 4
        for (int c2 = 0; c2 < 64; ++c2) {
            const f32x4 wv = *(const f32x4*)&Wl[c2 * 64 + fg * 4];
            #pragma unroll
            for (int m = 0; m < 4; ++m) {
                const float hv = ht[(ns * 4 + m) * 129 + half * 64 + c2];
                acc[m] += wv * hv;
            }
        }
    }

    const f32x4 a1v = *(const f32x4*)&a[fg * 4];
    const f32x4 a2v = *(const f32x4*)&a[NF + fg * 4];
    #pragma unroll
    for (int m = 0; m < 4; ++m) {
        float p1 = acc[m].x * a1v.x + acc[m].y * a1v.y + acc[m].z * a1v.z + acc[m].w * a1v.w;
        float p2 = acc[m].x * a2v.x + acc[m].y * a2v.y + acc[m].z * a2v.z + acc[m].w * a2v.w;
        #pragma unroll
        for (int d = 1; d < 16; d <<= 1) {
            p1 += __shfl_xor(p1, d, 64);
            p2 += __shfl_xor(p2, d, 64);
        }
        if (fg == 0) {
            const int n = n0 + ns * 4 + m;
            s1g[(size_t)b * NN + n] = p1;
            s2g[(size_t)b * NN + n] = p2;
        }
    }
    #pragma unroll
    for (int q = 0; q < 4; ++q) {
        f16x4 v;
        v[0] = (_Float16)acc[0][q]; v[1] = (_Float16)acc[1][q];
        v[2] = (_Float16)acc[2][q]; v[3] = (_Float16)acc[3][q];
        const int f = fg * 4 + q;
        *(f16x4*)&wht[((size_t)b * NF + f) * NN + n0 + ns * 4] = v;
    }
}

// Kernel 2: wave-autonomous flash-GAT.
// Wave = (16 rows, j-half). Lane l: row l&15, k-slice (l>>4)*8..+7 — exactly
// the MFMA A-frag layout, so P goes exp()->registers->MFMA with NO LDS and NO
// main-loop barriers. Fixed shift M_i = lrelu(s1_i + max_j s2_j) makes the
// two j-half partials additive (combined once at epilogue through LDS).
__global__ __launch_bounds__(512, 4) void k_attn(
    const float* __restrict__ g, const _Float16* __restrict__ wht,
    const float* __restrict__ s1g, const float* __restrict__ s2g,
    float* __restrict__ out)
{
    __shared__ float s2b[NN];            // 8 KB
    __shared__ float s1b[64];
    __shared__ float wred[8];
    __shared__ float SrowP[2][4][16];    // [jq][rg][row]
    __shared__ f32x4 accS[4][4][64];     // [rg][ft][lane] 16 KB

    const int t = threadIdx.x;
    const int lane = t & 63;
    const int w = t >> 6;
    const int rg = w & 3, jq = w >> 2;   // row-group, j-half
    const int b = blockIdx.x >> 5;
    const int i0 = (blockIdx.x & 31) << 6;

    // prologue: s2 -> LDS, s1 tile -> LDS, one-time max(s2) reduction
    const f32x4 s2v = *(const f32x4*)&s2g[(size_t)b * NN + t * 4];
    *(f32x4*)&s2b[t * 4] = s2v;
    if (t < 64) s1b[t] = s1g[(size_t)b * NN + i0 + t];
    float lm = fmaxf(fmaxf(s2v.x, s2v.y), fmaxf(s2v.z, s2v.w));
    #pragma unroll
    for (int d = 1; d < 64; d <<= 1) lm = fmaxf(lm, __shfl_xor(lm, d, 64));
    if (lane == 0) wred[w] = lm;
    __syncthreads();
    float S2MAX = wred[0];
    #pragma unroll
    for (int q = 1; q < 8; ++q) S2MAX = fmaxf(S2MAX, wred[q]);

    const int row = lane & 15;           // A-row / B-col / f-offset
    const int kg = lane >> 4;            // k-subgroup
    const float s1r = s1b[rg * 16 + row];
    const float M = lrelu(s1r + S2MAX);  // upper bound on this row's scores

    const float* gp = g + (size_t)b * NN * NN
                      + (size_t)(i0 + rg * 16 + row) * NN + jq * 1024 + kg * 8;
    const _Float16* wp0 = wht + ((size_t)b * NF + row) * NN + jq * 1024 + kg * 8;
    const _Float16* wp1 = wp0 + (size_t)16 * NN;
    const _Float16* wp2 = wp0 + (size_t)32 * NN;
    const _Float16* wp3 = wp0 + (size_t)48 * NN;
    const float* s2p = &s2b[jq * 1024 + kg * 8];

    f32x4 acc0 = {0,0,0,0}, acc1 = {0,0,0,0}, acc2 = {0,0,0,0}, acc3 = {0,0,0,0};
    float su = 0.0f;

    // depth-1 prefetch (named vars, rolled loop — no unroll blowup)
    f32x4 ga = *(const f32x4*)(gp);
    f32x4 gb = *(const f32x4*)(gp + 4);
    f16x8 w0 = *(const f16x8*)(wp0);
    f16x8 w1 = *(const f16x8*)(wp1);
    f16x8 w2 = *(const f16x8*)(wp2);
    f16x8 w3 = *(const f16x8*)(wp3);

    #pragma unroll 1
    for (int ch = 0; ch < 32; ++ch) {
        f32x4 nga = ga, ngb = gb;
        f16x8 nw0 = w0, nw1 = w1, nw2 = w2, nw3 = w3;
        if (ch < 31) {
            const int o = (ch + 1) * 32;
            nga = *(const f32x4*)(gp + o);
            ngb = *(const f32x4*)(gp + o + 4);
            nw0 = *(const f16x8*)(wp0 + o);
            nw1 = *(const f16x8*)(wp1 + o);
            nw2 = *(const f16x8*)(wp2 + o);
            nw3 = *(const f16x8*)(wp3 + o);
        }
        const f32x4 sv0 = *(const f32x4*)(s2p + ch * 32);
        const f32x4 sv1 = *(const f32x4*)(s2p + ch * 32 + 4);

        f16x8 af;
        #pragma unroll
        for (int u = 0; u < 4; ++u) {
            const float q0 = (ga[u] > 0.0f) ? __expf(lrelu(s1r + sv0[u]) - M) : 0.0f;
            su += q0;
            af[u] = (_Float16)q0;
            const float q1 = (gb[u] > 0.0f) ? __expf(lrelu(s1r + sv1[u]) - M) : 0.0f;
            su += q1;
            af[u + 4] = (_Float16)q1;
        }
        acc0 = __builtin_amdgcn_mfma_f32_16x16x32_f16(af, w0, acc0, 0, 0, 0);
        acc1 = __builtin_amdgcn_mfma_f32_16x16x32_f16(af, w1, acc1, 0, 0, 0);
        acc2 = __builtin_amdgcn_mfma_f32_16x16x32_f16(af, w2, acc2, 0, 0, 0);
        acc3 = __builtin_amdgcn_mfma_f32_16x16x32_f16(af, w3, acc3, 0, 0, 0);
        ga = nga; gb = ngb; w0 = nw0; w1 = nw1; w2 = nw2; w3 = nw3;
    }

    // ---- epilogue: combine j-halves, normalize, store ----
    su += __shfl_xor(su, 16, 64);        // reduce over k-subgroups (same row)
    su += __shfl_xor(su, 32, 64);
    if (lane < 16) SrowP[jq][rg][lane] = su;
    if (jq == 1) {
        accS[rg][0][lane] = acc0;
        accS[rg][1][lane] = acc1;
        accS[rg][2][lane] = acc2;
        accS[rg][3][lane] = acc3;
    }
    __syncthreads();
    if (jq == 0) {
        acc0 += accS[rg][0][lane];
        acc1 += accS[rg][1][lane];
        acc2 += accS[rg][2][lane];
        acc3 += accS[rg][3][lane];
        float rinv[4];
        #pragma unroll
        for (int r = 0; r < 4; ++r) {
            const int ri = kg * 4 + r;   // D row = (lane>>4)*4 + reg
            rinv[r] = 1.0f / (SrowP[0][rg][ri] + SrowP[1][rg][ri]);
        }
        const int ibase = i0 + rg * 16 + kg * 4;
        f32x4 o0, o1, o2, o3;
        #pragma unroll
        for (int r = 0; r < 4; ++r) {
            o0[r] = acc0[r] * rinv[r];
            o1[r] = acc1[r] * rinv[r];
            o2[r] = acc2[r] * rinv[r];
            o3[r] = acc3[r] * rinv[r];
        }
        *(f32x4*)&out[((size_t)b * NF + row) * NN + ibase] = o0;       // D col = lane&15
        *(f32x4*)&out[((size_t)b * NF + 16 + row) * NN + ibase] = o1;
        *(f32x4*)&out[((size_t)b * NF + 32 + row) * NN + ibase] = o2;
        *(f32x4*)&out[((size_t)b * NF + 48 + row) * NN + ibase] = o3;
    }
}

extern "C" void kernel_launch(void* const* d_in, const int* in_sizes, int n_in,
                              void* d_out, int out_size, void* d_ws, size_t ws_size,
                              hipStream_t stream)
{
    (void)in_sizes; (void)n_in; (void)out_size; (void)ws_size;
    const float* h = (const float*)d_in[0];
    const float* g = (const float*)d_in[1];
    const float* W = (const float*)d_in[2];
    const float* a = (const float*)d_in[3];
    float* out = (float*)d_out;

    // workspace: WhT f16 (4 MiB) | s1 (128 KiB) | s2 (128 KiB)
    char* ws = (char*)d_ws;
    _Float16* wht = (_Float16*)ws;
    float* s1 = (float*)(ws + (size_t)NB * NF * NN * sizeof(_Float16));
    float* s2 = s1 + (size_t)NB * NN;

    k_precompute<<<NB * (NN / 64), 256, 0, stream>>>(h, W, a, wht, s1, s2);
    k_attn<<<NB * (NN / 64), 512, 0, stream>>>(g, wht, s1, s2, out);
}

// Round 6
// 94.023 us; speedup vs baseline: 1.3849x; 1.1981x over previous
//
#include <hip/hip_runtime.h>
#include <hip/hip_bf16.h>

#define NB 16
#define NC 128
#define NN 2048
#define NF 64
#define NEG_SLOPE 0.33f
#define EXP_K 1.4426950408889634f   // log2(e): pre-scale so exp() is exp2()

typedef float    f32x2 __attribute__((ext_vector_type(2)));
typedef float    f32x4 __attribute__((ext_vector_type(4)));
typedef _Float16 f16x4 __attribute__((ext_vector_type(4)));
typedef _Float16 f16x8 __attribute__((ext_vector_type(8)));

__device__ __forceinline__ float lrelu(float x) {
    return fmaxf(x, x * NEG_SLOPE);   // valid leaky-relu for slope<1; commutes with positive scaling
}
__device__ __forceinline__ float rdfl(float v) {
    return __int_as_float(__builtin_amdgcn_readfirstlane(__float_as_int(v)));
}

// Kernel 1: Wh = h^T @ W in fp32 (VALU, LDS-tiled); emit WhT f16 [b][f][n],
// s1 = Wh@a1, s2 = Wh@a2 in fp32.  (unchanged)
__global__ __launch_bounds__(256) void k_precompute(
    const float* __restrict__ h, const float* __restrict__ W,
    const float* __restrict__ a, _Float16* __restrict__ wht,
    float* __restrict__ s1g, float* __restrict__ s2g)
{
    __shared__ float Wl[64 * 64];
    __shared__ float ht[64 * 129];

    const int t = threadIdx.x;
    const int b = blockIdx.x >> 5;
    const int n0 = (blockIdx.x & 31) << 6;
    const int lane = t & 63, cg = t >> 6;

    #pragma unroll 8
    for (int k = 0; k < 32; ++k) {
        const int c = cg * 32 + k;
        ht[lane * 129 + c] = h[(size_t)(b * NC + c) * NN + n0 + lane];
    }

    const int fg = t & 15, ns = t >> 4;
    f32x4 acc[4] = {};
    for (int half = 0; half < 2; ++half) {
        if (half) __syncthreads();
        #pragma unroll
        for (int k = 0; k < 4; ++k) {
            const int idx = k * 1024 + t * 4;
            *(f32x4*)&Wl[idx] = *(const f32x4*)&W[half * 4096 + idx];
        }
        __syncthreads();
        #pragma unroll 4
        for (int c2 = 0; c2 < 64; ++c2) {
            const f32x4 wv = *(const f32x4*)&Wl[c2 * 64 + fg * 4];
            #pragma unroll
            for (int m = 0; m < 4; ++m) {
                const float hv = ht[(ns * 4 + m) * 129 + half * 64 + c2];
                acc[m] += wv * hv;
            }
        }
    }

    const f32x4 a1v = *(const f32x4*)&a[fg * 4];
    const f32x4 a2v = *(const f32x4*)&a[NF + fg * 4];
    #pragma unroll
    for (int m = 0; m < 4; ++m) {
        float p1 = acc[m].x * a1v.x + acc[m].y * a1v.y + acc[m].z * a1v.z + acc[m].w * a1v.w;
        float p2 = acc[m].x * a2v.x + acc[m].y * a2v.y + acc[m].z * a2v.z + acc[m].w * a2v.w;
        #pragma unroll
        for (int d = 1; d < 16; d <<= 1) {
            p1 += __shfl_xor(p1, d, 64);
            p2 += __shfl_xor(p2, d, 64);
        }
        if (fg == 0) {
            const int n = n0 + ns * 4 + m;
            s1g[(size_t)b * NN + n] = p1;
            s2g[(size_t)b * NN + n] = p2;
        }
    }
    #pragma unroll
    for (int q = 0; q < 4; ++q) {
        f16x4 v;
        v[0] = (_Float16)acc[0][q]; v[1] = (_Float16)acc[1][q];
        v[2] = (_Float16)acc[2][q]; v[3] = (_Float16)acc[3][q];
        const int f = fg * 4 + q;
        *(f16x4*)&wht[((size_t)b * NF + f) * NN + n0 + ns * 4] = v;
    }
}

// Kernel 2: wave-autonomous flash-GAT, 64-col chunks.
// Wave owns 16 rows. Per chunk, issue order pinned by sched_barrier(0):
//   (a) 8 bf (wht) loads for THIS chunk      -> MFMA waits vmcnt(16): g-next stays in flight
//   (b) 16 g scalar loads for NEXT chunk     -> in-order vmcnt FIFO never drains these early
//   (c) P-gen (fixed bound shift, exp2), f16 -> wave-private swizzled LDS (no barrier)
//   (d) 2x ds_read_b128 A-frags; 8 PV MFMA + 2 ones-MFMA (exact row sums in acc_s)
// s1r/M live in SGPRs (readfirstlane). ~105 VGPR by construction.
__global__ __launch_bounds__(256, 4) void k_attn(
    const float* __restrict__ g, const _Float16* __restrict__ wht,
    const float* __restrict__ s1g, const float* __restrict__ s2g,
    float* __restrict__ out)
{
    __shared__ float s2b[NN];                        // 8 KB (pre-scaled by log2 e)
    __shared__ float s1b[64];
    __shared__ float wred[4];
    __shared__ __align__(16) _Float16 Pc[4][1024];   // per-wave 16 rows x 64 f16 (2 KB each)

    const int t = threadIdx.x;
    const int lane = t & 63;
    const int w = t >> 6;

    // XCD-pinned decode: p = (hi<<8)|(strip<<3)|xcd; b = xcd + 8*hi (bijective for 512 blocks)
    const int p = blockIdx.x;
    const int b = (p & 7) + ((p >> 8) << 3);
    const int strip = (p >> 3) & 31;
    const int i0 = strip * 64 + w * 16;              // wave's first row

    // ---- prologue: scaled s2 -> LDS, s1 tile, block max(s2) (the ONLY barrier) ----
    f32x4 sA = *(const f32x4*)&s2g[(size_t)b * NN + t * 8];
    f32x4 sB = *(const f32x4*)&s2g[(size_t)b * NN + t * 8 + 4];
    sA *= EXP_K; sB *= EXP_K;
    *(f32x4*)&s2b[t * 8] = sA;
    *(f32x4*)&s2b[t * 8 + 4] = sB;
    if (t < 64) s1b[t] = s1g[(size_t)b * NN + strip * 64 + t] * EXP_K;
    float lm = fmaxf(fmaxf(fmaxf(sA.x, sA.y), fmaxf(sA.z, sA.w)),
                     fmaxf(fmaxf(sB.x, sB.y), fmaxf(sB.z, sB.w)));
    #pragma unroll
    for (int d = 1; d < 64; d <<= 1) lm = fmaxf(lm, __shfl_xor(lm, d, 64));
    if (lane == 0) wred[w] = lm;
    __syncthreads();
    const float S2MAX = fmaxf(fmaxf(wred[0], wred[1]), fmaxf(wred[2], wred[3]));

    // wave-uniform per-row constants -> SGPRs
    float s1r[16], M[16];
    #pragma unroll
    for (int r = 0; r < 16; ++r) {
        const float v = s1b[w * 16 + r];
        s1r[r] = rdfl(v);
        M[r]   = rdfl(lrelu(v + S2MAX));             // scaled upper bound on row scores
    }

    const float* gp = g + (size_t)b * NN * NN + (size_t)i0 * NN + lane;
    const int fc = lane & 15, kg = lane >> 4;
    const _Float16* wb = wht + ((size_t)b * NF + fc) * NN + kg * 8;
    char* pcb = (char*)&Pc[w][0];

    f32x4 acc0 = {0,0,0,0}, acc1 = {0,0,0,0}, acc2 = {0,0,0,0}, acc3 = {0,0,0,0};
    f32x4 acc_s = {0,0,0,0};                         // row sums via ones-MFMA
    f16x8 ones;
    #pragma unroll
    for (int u = 0; u < 8; ++u) ones[u] = (_Float16)1.0f;

    float ga[16], gb[16];
    #pragma unroll
    for (int r = 0; r < 16; ++r) ga[r] = gp[(size_t)r * NN];   // chunk 0

#define CHUNK_BODY(CH, CUR, NXT)                                               \
    {                                                                          \
        /* (a) wht B-frags for THIS chunk */                                   \
        f16x8 bfv[2][4];                                                       \
        _Pragma("unroll")                                                      \
        for (int ks = 0; ks < 2; ++ks) {                                       \
            _Pragma("unroll")                                                  \
            for (int ft = 0; ft < 4; ++ft)                                     \
                bfv[ks][ft] = *(const f16x8*)(wb + (size_t)ft * 16 * NN        \
                                              + (CH) * 64 + ks * 32);          \
        }                                                                      \
        __builtin_amdgcn_sched_barrier(0);                                     \
        /* (b) g prefetch for next chunk */                                    \
        if ((CH) < 31) {                                                       \
            _Pragma("unroll")                                                  \
            for (int r = 0; r < 16; ++r)                                       \
                NXT[r] = gp[(size_t)r * NN + ((CH) + 1) * 64];                 \
        }                                                                      \
        __builtin_amdgcn_sched_barrier(0);                                     \
        /* (c) P-gen: streaming layout -> wave-private LDS (swizzled) */       \
        const float sv = s2b[(CH) * 64 + lane];                                \
        _Pragma("unroll")                                                      \
        for (int r = 0; r < 16; ++r) {                                         \
            const float arg = lrelu(s1r[r] + sv) - M[r];                       \
            const float pe  = (CUR[r] > 0.0f) ? __builtin_amdgcn_exp2f(arg) : 0.0f; \
            *(_Float16*)(pcb + ((r * 128 + lane * 2) ^ ((r & 7) << 4))) = (_Float16)pe; \
        }                                                                      \
        /* (d) A-frags + MFMA (incl. ones-MFMA row sums) */                    \
        _Pragma("unroll")                                                      \
        for (int ks = 0; ks < 2; ++ks) {                                       \
            const f16x8 af = *(const f16x8*)(pcb +                             \
                ((fc * 128 + ks * 64 + kg * 16) ^ ((fc & 7) << 4)));           \
            acc0  = __builtin_amdgcn_mfma_f32_16x16x32_f16(af, bfv[ks][0], acc0, 0, 0, 0); \
            acc1  = __builtin_amdgcn_mfma_f32_16x16x32_f16(af, bfv[ks][1], acc1, 0, 0, 0); \
            acc2  = __builtin_amdgcn_mfma_f32_16x16x32_f16(af, bfv[ks][2], acc2, 0, 0, 0); \
            acc3  = __builtin_amdgcn_mfma_f32_16x16x32_f16(af, bfv[ks][3], acc3, 0, 0, 0); \
            acc_s = __builtin_amdgcn_mfma_f32_16x16x32_f16(af, ones,       acc_s, 0, 0, 0); \
        }                                                                      \
    }

    #pragma unroll 1
    for (int it = 0; it < 16; ++it) {
        CHUNK_BODY(it * 2,     ga, gb);
        CHUNK_BODY(it * 2 + 1, gb, ga);
    }
#undef CHUNK_BODY

    // ---- epilogue: acc_s holds exact row sums (row m = kg*4+q, any col) ----
    f32x4 rinv;
    #pragma unroll
    for (int q = 0; q < 4; ++q) rinv[q] = 1.0f / acc_s[q];

    const size_t ob = ((size_t)b * NF + fc) * NN + (size_t)i0 + kg * 4;
    f32x4 o0, o1, o2, o3;
    #pragma unroll
    for (int q = 0; q < 4; ++q) {        // D row m = kg*4+q (m89-verified), col = fc
        o0[q] = acc0[q] * rinv[q];
        o1[q] = acc1[q] * rinv[q];
        o2[q] = acc2[q] * rinv[q];
        o3[q] = acc3[q] * rinv[q];
    }
    *(f32x4*)&out[ob]                   = o0;
    *(f32x4*)&out[ob + (size_t)16 * NN] = o1;
    *(f32x4*)&out[ob + (size_t)32 * NN] = o2;
    *(f32x4*)&out[ob + (size_t)48 * NN] = o3;
}

extern "C" void kernel_launch(void* const* d_in, const int* in_sizes, int n_in,
                              void* d_out, int out_size, void* d_ws, size_t ws_size,
                              hipStream_t stream)
{
    (void)in_sizes; (void)n_in; (void)out_size; (void)ws_size;
    const float* h = (const float*)d_in[0];
    const float* g = (const float*)d_in[1];
    const float* W = (const float*)d_in[2];
    const float* a = (const float*)d_in[3];
    float* out = (float*)d_out;

    // workspace: WhT f16 (4 MiB) | s1 (128 KiB) | s2 (128 KiB)
    char* ws = (char*)d_ws;
    _Float16* wht = (_Float16*)ws;
    float* s1 = (float*)(ws + (size_t)NB * NF * NN * sizeof(_Float16));
    float* s2 = s1 + (size_t)NB * NN;

    k_precompute<<<NB * (NN / 64), 256, 0, stream>>>(h, W, a, wht, s1, s2);
    k_attn<<<NB * (NN / 64), 256, 0, stream>>>(g, wht, s1, s2, out);   // 512 blocks (grid bug fixed)
}